// Round 1
// baseline (492.199 us; speedup 1.0000x reference)
//
#include <hip/hip_runtime.h>

// Problem constants
#define M_  2049
#define B_  16
#define N_  1024

__device__ __forceinline__ double two_pi() { return 6.283185307179586476925286766559; }

// ---------------------------------------------------------------------------
// Kernel A: gsum[b][m] = sum_n exp(-(u_n - u_m)^2 / (4 tau))
// u_n = x[b][n] * (2pi/10), u_m = 2pi*m/M.  No periodic wrap (matches ref).
// ---------------------------------------------------------------------------
__global__ void gsum_kernel(const float* __restrict__ x, double* __restrict__ gsum) {
    __shared__ float xs[N_];
    const int b = blockIdx.y;
    for (int i = threadIdx.x; i < N_; i += blockDim.x) xs[i] = x[b * N_ + i];
    __syncthreads();
    const int m = blockIdx.x * blockDim.x + threadIdx.x;
    if (m >= M_) return;
    const double um      = two_pi() * (double)m / (double)M_;
    const double scale   = two_pi() / 10.0;
    const double inv4tau = 1.0 / (4.0 * 2.821e-5);
    double acc = 0.0;
    for (int n = 0; n < N_; ++n) {
        double d = (double)xs[n] * scale - um;
        double t = d * d * inv4tau;
        if (t < 745.0) acc += exp(-t);   // exp underflows to 0 beyond this anyway
    }
    gsum[b * M_ + m] = acc;
}

// ---------------------------------------------------------------------------
// Kernel B1: W~[c][j] = (L/2pi) * deconv(j)^2 * mult_c(j^2),  j = 0..1024
// (even symmetric part of the frequency-domain multiplier, in FFT index order)
// ---------------------------------------------------------------------------
__global__ void wt_kernel(const float* __restrict__ s0, const float* __restrict__ a0,
                          const float* __restrict__ s1, const float* __restrict__ a1,
                          double* __restrict__ Wt) {
    const int idx = blockIdx.x * blockDim.x + threadIdx.x;
    if (idx >= 2 * 1025) return;
    const int c = idx / 1025, j = idx % 1025;
    const double TAU = 2.821e-5;
    const double PI_ = 3.14159265358979323846;
    double k2   = (double)j * (double)j;
    double dec  = sqrt(PI_ / TAU) * exp(TAU * k2);
    double base = (10.0 / (2.0 * PI_)) * dec * dec;
    double mult;
    if (c == 0) {
        double s = 5.0 * (double)s0[0];
        mult = -(double)a0[0] * 4.0 * PI_ / (k2 + s * s);
    } else {
        double s = 5.0 * (double)s1[0];
        double den = k2 + s * s;
        mult = (double)a1[0] * 4.0 * PI_ / (den * den);
    }
    Wt[c * 1025 + j] = base * mult;
}

// ---------------------------------------------------------------------------
// Kernel B2: h_c[d] = (1/M) * ( W~[c][0] + 2 * sum_{j=1..1024} W~[c][j] cos(2pi j d / M) )
// Real even circular-convolution kernel equivalent to the whole
// fftshift/deconv/mult/deconv/ifftshift/ifft chain.
// ---------------------------------------------------------------------------
__global__ void h_kernel(const double* __restrict__ Wt, double* __restrict__ h) {
    __shared__ double w[1025];
    const int c = blockIdx.y;
    for (int i = threadIdx.x; i < 1025; i += blockDim.x) w[i] = Wt[c * 1025 + i];
    __syncthreads();
    const int d = blockIdx.x * blockDim.x + threadIdx.x;
    if (d >= M_) return;
    const double ang0 = two_pi() / (double)M_;
    double acc = w[0];
    for (int j = 1; j <= 1024; ++j) {
        int r = (j * d) % M_;                  // exact integer phase reduction
        acc += 2.0 * w[j] * cos(ang0 * (double)r);
    }
    h[c * M_ + d] = acc / (double)M_;
}

// ---------------------------------------------------------------------------
// Kernel C: conv[b][c][m] = sum_{m'} gsum[b][m'] * h_c[(m - m') mod M]   (== irfft)
// ---------------------------------------------------------------------------
__global__ void conv_kernel(const double* __restrict__ gsum, const double* __restrict__ h,
                            double* __restrict__ conv) {
    __shared__ double gs[M_];
    const int b = blockIdx.z, c = blockIdx.y;
    for (int i = threadIdx.x; i < M_; i += blockDim.x) gs[i] = gsum[b * M_ + i];
    __syncthreads();
    const int m = blockIdx.x * blockDim.x + threadIdx.x;
    if (m >= M_) return;
    const double* hc = h + c * M_;
    double acc = 0.0;
    for (int mp = 0; mp <= m; ++mp)        acc += gs[mp] * hc[m - mp];
    for (int mp = m + 1; mp < M_; ++mp)    acc += gs[mp] * hc[m - mp + M_];
    conv[(b * 2 + c) * M_ + m] = acc;
}

// ---------------------------------------------------------------------------
// Kernel D: fmm[b][n][c] = (1/M) * sum_m g[b,n,m] * conv[b][c][m]
// g support is < +-96 grid bins (exp(-t) double-underflows beyond).
// ---------------------------------------------------------------------------
__global__ void fmm_kernel(const float* __restrict__ x, const double* __restrict__ conv,
                           float* __restrict__ out) {
    const int t = blockIdx.x * blockDim.x + threadIdx.x;
    if (t >= B_ * N_) return;
    const int b = t / N_, n = t % N_;
    const double du      = two_pi() / (double)M_;
    const double inv4tau = 1.0 / (4.0 * 2.821e-5);
    double u = (double)x[b * N_ + n] * (two_pi() / 10.0);
    int mc = (int)(u / du + 0.5);
    int lo = mc - 96; if (lo < 0) lo = 0;
    int hi = mc + 96; if (hi > M_ - 1) hi = M_ - 1;
    const double* c0 = conv + (b * 2 + 0) * M_;
    const double* c1 = conv + (b * 2 + 1) * M_;
    double a0 = 0.0, a1 = 0.0;
    for (int m = lo; m <= hi; ++m) {
        double d = u - du * (double)m;
        double g = exp(-d * d * inv4tau);   // underflows to 0.0 harmlessly at window edge
        a0 += g * c0[m];
        a1 += g * c1[m];
    }
    out[t * 2 + 0] = (float)(a0 / (double)M_);
    out[t * 2 + 1] = (float)(a1 / (double)M_);
}

// ---------------------------------------------------------------------------
extern "C" void kernel_launch(void* const* d_in, const int* in_sizes, int n_in,
                              void* d_out, int out_size, void* d_ws, size_t ws_size,
                              hipStream_t stream) {
    (void)in_sizes; (void)n_in; (void)out_size; (void)ws_size;
    const float* x  = (const float*)d_in[0];
    const float* s0 = (const float*)d_in[1];
    const float* a0 = (const float*)d_in[2];
    const float* s1 = (const float*)d_in[3];
    const float* a1 = (const float*)d_in[4];
    float* out = (float*)d_out;

    // Workspace layout (all f64, 8B aligned): total ~836 KB
    double* gsum = (double*)d_ws;           // B_*M_      = 32784
    double* Wt   = gsum + B_ * M_;          // 2*1025     =  2050
    double* h    = Wt + 2 * 1025;           // 2*M_       =  4098
    double* conv = h + 2 * M_;              // B_*2*M_    = 65568

    const int BS = 256;
    const int MT = (M_ + BS - 1) / BS;      // 9 tiles over the mesh

    hipLaunchKernelGGL(gsum_kernel, dim3(MT, B_), dim3(BS), 0, stream, x, gsum);
    hipLaunchKernelGGL(wt_kernel, dim3((2 * 1025 + BS - 1) / BS), dim3(BS), 0, stream,
                       s0, a0, s1, a1, Wt);
    hipLaunchKernelGGL(h_kernel, dim3(MT, 2), dim3(BS), 0, stream, Wt, h);
    hipLaunchKernelGGL(conv_kernel, dim3(MT, 2, B_), dim3(BS), 0, stream, gsum, h, conv);
    hipLaunchKernelGGL(fmm_kernel, dim3((B_ * N_ + BS - 1) / BS), dim3(BS), 0, stream,
                       x, conv, out);
}

// Round 2
// 231.995 us; speedup vs baseline: 2.1216x; 2.1216x over previous
//
#include <hip/hip_runtime.h>
#include <math.h>

#define M_   2049
#define B_   16
#define N_   1024
#define TAU_ 2.821e-5
#define PI_  3.14159265358979323846
#define TWO_PI_ 6.283185307179586476925286766559

#define GS_SPLIT 4      // n-split for gsum_kernel
#define H_JSPLIT 8      // j-split for h_kernel (chunks of 128 over j=1..1024)

// ---------------------------------------------------------------------------
// gsum[b][m] += sum over this block's n-chunk of exp(-(u_n - u_m)^2 / 4tau)
// f64 argument, f32 exp (abs err ~1e-7 per term; output amplification budget
// allows ~2.5e-3 on gsum bins -> 100x margin).  Requires gsum pre-zeroed.
// ---------------------------------------------------------------------------
__global__ void gsum_kernel(const float* __restrict__ x, double* __restrict__ gsum) {
    __shared__ float xs[N_ / GS_SPLIT];   // 256 floats
    const int b = blockIdx.y;
    const int nlo = blockIdx.z * (N_ / GS_SPLIT);
    xs[threadIdx.x] = x[b * N_ + nlo + threadIdx.x];
    __syncthreads();
    const int m = blockIdx.x * 256 + threadIdx.x;
    if (m >= M_) return;
    const double um      = TWO_PI_ * (double)m / (double)M_;
    const double scale   = TWO_PI_ / 10.0;
    const double inv4tau = 1.0 / (4.0 * TAU_);
    double acc = 0.0;
    for (int i = 0; i < N_ / GS_SPLIT; ++i) {
        double d = (double)xs[i] * scale - um;
        double t = d * d * inv4tau;
        if (t < 88.0) acc += (double)__expf(-(float)t);   // f32 exp underflows past 88
    }
    atomicAdd(&gsum[b * M_ + m], acc);
}

// ---------------------------------------------------------------------------
// hhalf[c][d] (d = 0..1024) = (1/M)(W0 + 2 sum_{j=1..1024} Wj cos(2pi j d / M))
// cos(2pi j d / M) takes only M distinct values -> per-block LDS table + exact
// incremental (j*d) mod M.  j-split across blocks, atomicAdd into hhalf
// (pre-zeroed).  W_c[j] = (L/2pi) * deconv(j)^2 * mult_c(j^2).
// ---------------------------------------------------------------------------
__global__ void h_kernel(const float* __restrict__ s0, const float* __restrict__ a0,
                         const float* __restrict__ s1, const float* __restrict__ a1,
                         double* __restrict__ hhalf) {
    __shared__ double costab[M_];          // 16392 B
    __shared__ double coeff[1024 / H_JSPLIT]; // 128 doubles: 2*W_c[j]/M for this chunk
    const int c  = blockIdx.z;
    const int jc = blockIdx.y;
    const int jlo = 1 + jc * (1024 / H_JSPLIT);

    for (int i = threadIdx.x; i < M_; i += 256)
        costab[i] = cos(TWO_PI_ * (double)i / (double)M_);

    if (threadIdx.x < 1024 / H_JSPLIT) {
        int j = jlo + threadIdx.x;
        double k2   = (double)j * (double)j;
        double dec2 = (PI_ / TAU_) * exp(2.0 * TAU_ * k2);   // deconv^2
        double mult;
        if (c == 0) {
            double s = 5.0 * (double)s0[0];
            mult = -(double)a0[0] * 4.0 * PI_ / (k2 + s * s);
        } else {
            double s = 5.0 * (double)s1[0];
            double den = k2 + s * s;
            mult = (double)a1[0] * 4.0 * PI_ / (den * den);
        }
        coeff[threadIdx.x] = 2.0 * (10.0 / TWO_PI_) * dec2 * mult / (double)M_;
    }
    __syncthreads();

    const int d = blockIdx.x * 256 + threadIdx.x;
    if (d > 1024) return;

    double acc = 0.0;
    if (jc == 0) {   // j = 0 term, added once
        double mult0;
        if (c == 0) {
            double s = 5.0 * (double)s0[0];
            mult0 = -(double)a0[0] * 4.0 * PI_ / (s * s);
        } else {
            double s = 5.0 * (double)s1[0];
            mult0 = (double)a1[0] * 4.0 * PI_ / ((s * s) * (s * s));
        }
        acc = (10.0 / TWO_PI_) * (PI_ / TAU_) * mult0 / (double)M_;
    }

    int r = (int)(((long long)jlo * (long long)d) % M_);
    #pragma unroll 4
    for (int jj = 0; jj < 1024 / H_JSPLIT; ++jj) {
        acc += coeff[jj] * costab[r];
        r += d; if (r >= M_) r -= M_;
    }
    atomicAdd(&hhalf[c * 1025 + d], acc);
}

// ---------------------------------------------------------------------------
// conv[b][c][m] = sum_mp gsum[b][mp] * h_c[(m - mp) mod M]
// h staged to LDS with even-symmetry mirror; gsum read wave-uniform (scalar).
// ---------------------------------------------------------------------------
__global__ void conv_kernel(const double* __restrict__ gsum, const double* __restrict__ hhalf,
                            double* __restrict__ conv) {
    __shared__ double hcs[M_];
    const int c = blockIdx.y, b = blockIdx.z;
    for (int i = threadIdx.x; i <= 1024; i += 256) {
        double v = hhalf[c * 1025 + i];
        hcs[i] = v;
        if (i > 0) hcs[M_ - i] = v;    // h is even: h[M-d] = h[d]
    }
    __syncthreads();
    const int m = blockIdx.x * 256 + threadIdx.x;
    if (m >= M_) return;
    const double* gs = gsum + b * M_;
    double acc = 0.0;
    int r = m;
    #pragma unroll 4
    for (int mp = 0; mp < M_; ++mp) {
        acc += gs[mp] * hcs[r];
        --r; if (r < 0) r += M_;
    }
    conv[(b * 2 + c) * M_ + m] = acc;
}

// ---------------------------------------------------------------------------
// fmm[b][n][c] = (1/M) sum_m g[b,n,m] * conv[b][c][m]
// f32 exp underflows past t=88 -> +-34 bin window (matches reference's own
// f32 underflow; dropped tails contribute < 1e-19 of output scale).
// ---------------------------------------------------------------------------
__global__ void fmm_kernel(const float* __restrict__ x, const double* __restrict__ conv,
                           float* __restrict__ out) {
    const int t = blockIdx.x * 256 + threadIdx.x;
    if (t >= B_ * N_) return;
    const int b = t / N_;
    const double du      = TWO_PI_ / (double)M_;
    const double inv4tau = 1.0 / (4.0 * TAU_);
    const double u = (double)x[t] * (TWO_PI_ / 10.0);
    int mc = (int)(u / du + 0.5);
    int lo = mc - 34; if (lo < 0) lo = 0;
    int hi = mc + 34; if (hi > M_ - 1) hi = M_ - 1;
    const double* c0 = conv + (b * 2 + 0) * (size_t)M_;
    const double* c1 = c0 + M_;
    double a0 = 0.0, a1 = 0.0;
    for (int m = lo; m <= hi; ++m) {
        double d = u - du * (double)m;
        double g = (double)__expf(-(float)(d * d * inv4tau));
        a0 += g * c0[m];
        a1 += g * c1[m];
    }
    out[t * 2 + 0] = (float)(a0 / (double)M_);
    out[t * 2 + 1] = (float)(a1 / (double)M_);
}

// ---------------------------------------------------------------------------
extern "C" void kernel_launch(void* const* d_in, const int* in_sizes, int n_in,
                              void* d_out, int out_size, void* d_ws, size_t ws_size,
                              hipStream_t stream) {
    (void)in_sizes; (void)n_in; (void)out_size; (void)ws_size;
    const float* x  = (const float*)d_in[0];
    const float* s0 = (const float*)d_in[1];
    const float* a0 = (const float*)d_in[2];
    const float* s1 = (const float*)d_in[3];
    const float* a1 = (const float*)d_in[4];
    float* out = (float*)d_out;

    // Workspace layout (f64): [gsum B*M | hhalf 2*1025 | conv B*2*M]
    double* gsum  = (double*)d_ws;             // 32784
    double* hhalf = gsum + B_ * M_;            // 2050
    double* conv  = hhalf + 2 * 1025;          // 65568

    // Zero the atomic-accumulated regions (gsum + hhalf)
    hipMemsetAsync(d_ws, 0, (size_t)(B_ * M_ + 2 * 1025) * sizeof(double), stream);

    hipLaunchKernelGGL(gsum_kernel, dim3(9, B_, GS_SPLIT), dim3(256), 0, stream, x, gsum);
    hipLaunchKernelGGL(h_kernel, dim3(5, H_JSPLIT, 2), dim3(256), 0, stream,
                       s0, a0, s1, a1, hhalf);
    hipLaunchKernelGGL(conv_kernel, dim3(9, 2, B_), dim3(256), 0, stream, gsum, hhalf, conv);
    hipLaunchKernelGGL(fmm_kernel, dim3((B_ * N_ + 255) / 256), dim3(256), 0, stream,
                       x, conv, out);
}

// Round 3
// 136.571 us; speedup vs baseline: 3.6040x; 1.6987x over previous
//
#include <hip/hip_runtime.h>
#include <math.h>

#define M_   2049
#define B_   16
#define N_   1024
#define TAU_ 2.821e-5
#define PI_  3.14159265358979323846
#define TWO_PI_ 6.283185307179586476925286766559

#define GS_SPLIT 4      // n-split for gsum_kernel
#define H_JSPLIT 8      // j-split for h_kernel (chunks of 128 over j=1..1024)

// ---------------------------------------------------------------------------
// gsum[b][m] += sum over this block's n-chunk of exp(-(u_n - u_m)^2 / 4tau)
// f64 argument, f32 exp.  Requires gsum pre-zeroed.
// ---------------------------------------------------------------------------
__global__ void gsum_kernel(const float* __restrict__ x, double* __restrict__ gsum) {
    __shared__ float xs[N_ / GS_SPLIT];   // 256 floats
    const int b = blockIdx.y;
    const int nlo = blockIdx.z * (N_ / GS_SPLIT);
    xs[threadIdx.x] = x[b * N_ + nlo + threadIdx.x];
    __syncthreads();
    const int m = blockIdx.x * 256 + threadIdx.x;
    if (m >= M_) return;
    const double um      = TWO_PI_ * (double)m / (double)M_;
    const double scale   = TWO_PI_ / 10.0;
    const double inv4tau = 1.0 / (4.0 * TAU_);
    double acc = 0.0;
    for (int i = 0; i < N_ / GS_SPLIT; ++i) {
        double d = (double)xs[i] * scale - um;
        double t = d * d * inv4tau;
        if (t < 88.0) acc += (double)__expf(-(float)t);   // f32 exp underflows past 88
    }
    atomicAdd(&gsum[b * M_ + m], acc);
}

// ---------------------------------------------------------------------------
// hhalf[c][d] (d = 0..1024) = (1/M)(W0 + 2 sum_{j=1..1024} Wj cos(2pi j d / M))
// cos via per-block LDS table + exact incremental (j*d) mod M.  j-split
// across blocks, atomicAdd into pre-zeroed hhalf.
// ---------------------------------------------------------------------------
__global__ void h_kernel(const float* __restrict__ s0, const float* __restrict__ a0,
                         const float* __restrict__ s1, const float* __restrict__ a1,
                         double* __restrict__ hhalf) {
    __shared__ double costab[M_];
    __shared__ double coeff[1024 / H_JSPLIT];
    const int c  = blockIdx.z;
    const int jc = blockIdx.y;
    const int jlo = 1 + jc * (1024 / H_JSPLIT);

    for (int i = threadIdx.x; i < M_; i += 256)
        costab[i] = cos(TWO_PI_ * (double)i / (double)M_);

    if (threadIdx.x < 1024 / H_JSPLIT) {
        int j = jlo + threadIdx.x;
        double k2   = (double)j * (double)j;
        double dec2 = (PI_ / TAU_) * exp(2.0 * TAU_ * k2);   // deconv^2
        double mult;
        if (c == 0) {
            double s = 5.0 * (double)s0[0];
            mult = -(double)a0[0] * 4.0 * PI_ / (k2 + s * s);
        } else {
            double s = 5.0 * (double)s1[0];
            double den = k2 + s * s;
            mult = (double)a1[0] * 4.0 * PI_ / (den * den);
        }
        coeff[threadIdx.x] = 2.0 * (10.0 / TWO_PI_) * dec2 * mult / (double)M_;
    }
    __syncthreads();

    const int d = blockIdx.x * 256 + threadIdx.x;
    if (d > 1024) return;

    double acc = 0.0;
    if (jc == 0) {   // j = 0 term, added once
        double mult0;
        if (c == 0) {
            double s = 5.0 * (double)s0[0];
            mult0 = -(double)a0[0] * 4.0 * PI_ / (s * s);
        } else {
            double s = 5.0 * (double)s1[0];
            mult0 = (double)a1[0] * 4.0 * PI_ / ((s * s) * (s * s));
        }
        acc = (10.0 / TWO_PI_) * (PI_ / TAU_) * mult0 / (double)M_;
    }

    int r = (int)(((long long)jlo * (long long)d) % M_);
    #pragma unroll 4
    for (int jj = 0; jj < 1024 / H_JSPLIT; ++jj) {
        acc += coeff[jj] * costab[r];
        r += d; if (r >= M_) r -= M_;
    }
    atomicAdd(&hhalf[c * 1025 + d], acc);
}

// ---------------------------------------------------------------------------
// conv[b][c][m] += sum over this block's mp-chunk of gsum[b][mp]*h_c[(m-mp) mod M]
// h window staged to LDS (mirror+mod folded at staging -> wrap-free inner
// loop); gs read wave-uniform from global (scalar path); 4 independent f64
// accumulators.  mp split 2-way; f64 atomicAdd into pre-zeroed conv.
// ---------------------------------------------------------------------------
__global__ void conv_kernel(const double* __restrict__ gsum, const double* __restrict__ hhalf,
                            double* __restrict__ conv) {
    __shared__ double hwin[1280];
    const int mt = blockIdx.x;          // m-tile, 0..8
    const int c  = blockIdx.y;
    const int b  = blockIdx.z >> 1;
    const int s  = blockIdx.z & 1;      // mp-chunk
    const int m0  = mt * 256;
    const int p0  = s ? 1025 : 0;
    const int len = s ? 1024 : 1025;
    const int base = m0 - (p0 + len - 1) + M_;   // >= 1
    const int win  = 255 + len;
    const double* hh = hhalf + c * 1025;
    for (int i = threadIdx.x; i < win; i += 256) {
        int idx = base + i;
        while (idx >= M_) idx -= M_;
        int d = (idx > 1024) ? (M_ - idx) : idx;   // h even: h[d] = hhalf[min(d,M-d)]
        hwin[i] = hh[d];
    }
    __syncthreads();
    const int m = m0 + threadIdx.x;
    if (m >= M_) return;
    const double* gs = gsum + (size_t)b * M_ + p0;   // wave-uniform index -> s_load
    const int i0 = (m - m0) + len - 1;
    double a0 = 0.0, a1 = 0.0, a2 = 0.0, a3 = 0.0;
    int mp = 0;
    #pragma unroll 2
    for (; mp + 3 < len; mp += 4) {
        double g0 = gs[mp+0], g1 = gs[mp+1], g2 = gs[mp+2], g3 = gs[mp+3];
        const double* hp = hwin + (i0 - mp);
        a0 += g0 * hp[0];
        a1 += g1 * hp[-1];
        a2 += g2 * hp[-2];
        a3 += g3 * hp[-3];
    }
    for (; mp < len; ++mp) a0 += gs[mp] * hwin[i0 - mp];
    atomicAdd(&conv[((size_t)b * 2 + c) * M_ + m], (a0 + a1) + (a2 + a3));
}

// ---------------------------------------------------------------------------
// fmm[b][n][c] = (1/M) sum_m g[b,n,m] * conv[b][c][m]
// 4 lanes per point: 4x parallelism, contiguous 32B quad reads, shfl reduce.
// ---------------------------------------------------------------------------
__global__ void fmm_kernel(const float* __restrict__ x, const double* __restrict__ conv,
                           float* __restrict__ out) {
    const int gid = blockIdx.x * 256 + threadIdx.x;
    const int pt  = gid >> 2;          // point id = b*N + n
    const int sub = gid & 3;
    const int b   = pt >> 10;          // / N_
    const double du      = TWO_PI_ / (double)M_;
    const double inv4tau = 1.0 / (4.0 * TAU_);
    const double u = (double)x[pt] * (TWO_PI_ / 10.0);
    int mc = (int)(u / du + 0.5);
    int lo = mc - 34; if (lo < 0) lo = 0;
    int hi = mc + 34; if (hi > M_ - 1) hi = M_ - 1;
    const double* c0 = conv + (size_t)(b * 2) * M_;
    const double* c1 = c0 + M_;
    double a0 = 0.0, a1 = 0.0;
    for (int m = lo + sub; m <= hi; m += 4) {
        double d = u - du * (double)m;
        double g = (double)__expf(-(float)(d * d * inv4tau));
        a0 += g * c0[m];
        a1 += g * c1[m];
    }
    a0 += __shfl_xor(a0, 1); a1 += __shfl_xor(a1, 1);
    a0 += __shfl_xor(a0, 2); a1 += __shfl_xor(a1, 2);
    if (sub == 0) {
        out[pt * 2 + 0] = (float)(a0 / (double)M_);
        out[pt * 2 + 1] = (float)(a1 / (double)M_);
    }
}

// ---------------------------------------------------------------------------
extern "C" void kernel_launch(void* const* d_in, const int* in_sizes, int n_in,
                              void* d_out, int out_size, void* d_ws, size_t ws_size,
                              hipStream_t stream) {
    (void)in_sizes; (void)n_in; (void)out_size; (void)ws_size;
    const float* x  = (const float*)d_in[0];
    const float* s0 = (const float*)d_in[1];
    const float* a0 = (const float*)d_in[2];
    const float* s1 = (const float*)d_in[3];
    const float* a1 = (const float*)d_in[4];
    float* out = (float*)d_out;

    // Workspace layout (f64, contiguous): [gsum B*M | hhalf 2*1025 | conv B*2*M]
    double* gsum  = (double*)d_ws;             // 32784
    double* hhalf = gsum + B_ * M_;            // 2050
    double* conv  = hhalf + 2 * 1025;          // 65568

    // Zero all atomic-accumulated regions in one shot (~803 KB)
    hipMemsetAsync(d_ws, 0, (size_t)(B_ * M_ + 2 * 1025 + B_ * 2 * M_) * sizeof(double), stream);

    hipLaunchKernelGGL(gsum_kernel, dim3(9, B_, GS_SPLIT), dim3(256), 0, stream, x, gsum);
    hipLaunchKernelGGL(h_kernel, dim3(5, H_JSPLIT, 2), dim3(256), 0, stream,
                       s0, a0, s1, a1, hhalf);
    hipLaunchKernelGGL(conv_kernel, dim3(9, 2, 32), dim3(256), 0, stream, gsum, hhalf, conv);
    hipLaunchKernelGGL(fmm_kernel, dim3(B_ * N_ * 4 / 256), dim3(256), 0, stream,
                       x, conv, out);
}

// Round 4
// 117.731 us; speedup vs baseline: 4.1807x; 1.1600x over previous
//
#include <hip/hip_runtime.h>
#include <math.h>

#define M_   2049
#define B_   16
#define N_   1024
#define TAU_ 2.821e-5
#define PI_  3.14159265358979323846
#define TWO_PI_ 6.283185307179586476925286766559

#define GS_SPLIT 4      // n-split for gsum_kernel
#define H_JSPLIT 16     // j-split for h_kernel (chunks of 64 over j=1..1024)
#define CV_SPLIT 8      // mp-split for conv_kernel
#define FMM_LPP  16     // lanes per point in fmm_kernel

// ---------------------------------------------------------------------------
// gsum[b][m] += sum over this block's n-chunk of exp(-(u_n - u_m)^2 / 4tau)
// f64 argument, f32 exp.  Requires gsum pre-zeroed.
// ---------------------------------------------------------------------------
__global__ void gsum_kernel(const float* __restrict__ x, double* __restrict__ gsum) {
    __shared__ float xs[N_ / GS_SPLIT];   // 256 floats
    const int b = blockIdx.y;
    const int nlo = blockIdx.z * (N_ / GS_SPLIT);
    xs[threadIdx.x] = x[b * N_ + nlo + threadIdx.x];
    __syncthreads();
    const int m = blockIdx.x * 256 + threadIdx.x;
    if (m >= M_) return;
    const double um      = TWO_PI_ * (double)m / (double)M_;
    const double scale   = TWO_PI_ / 10.0;
    const double inv4tau = 1.0 / (4.0 * TAU_);
    double acc = 0.0;
    for (int i = 0; i < N_ / GS_SPLIT; ++i) {
        double d = (double)xs[i] * scale - um;
        double t = d * d * inv4tau;
        if (t < 88.0) acc += (double)__expf(-(float)t);   // f32 exp underflows past 88
    }
    atomicAdd(&gsum[b * M_ + m], acc);
}

// ---------------------------------------------------------------------------
// hhalf[c][d] (d = 0..1024) = (1/M)(W0 + 2 sum_{j=1..1024} Wj cos(2pi j d / M))
// cos via per-block LDS table + exact incremental (j*d) mod M.  j-split
// across blocks, atomicAdd into pre-zeroed hhalf.
// ---------------------------------------------------------------------------
__global__ void h_kernel(const float* __restrict__ s0, const float* __restrict__ a0,
                         const float* __restrict__ s1, const float* __restrict__ a1,
                         double* __restrict__ hhalf) {
    __shared__ double costab[M_];
    __shared__ double coeff[1024 / H_JSPLIT];
    const int c  = blockIdx.z;
    const int jc = blockIdx.y;
    const int jlo = 1 + jc * (1024 / H_JSPLIT);

    for (int i = threadIdx.x; i < M_; i += 256)
        costab[i] = cos(TWO_PI_ * (double)i / (double)M_);

    if (threadIdx.x < 1024 / H_JSPLIT) {
        int j = jlo + threadIdx.x;
        double k2   = (double)j * (double)j;
        double dec2 = (PI_ / TAU_) * exp(2.0 * TAU_ * k2);   // deconv^2
        double mult;
        if (c == 0) {
            double s = 5.0 * (double)s0[0];
            mult = -(double)a0[0] * 4.0 * PI_ / (k2 + s * s);
        } else {
            double s = 5.0 * (double)s1[0];
            double den = k2 + s * s;
            mult = (double)a1[0] * 4.0 * PI_ / (den * den);
        }
        coeff[threadIdx.x] = 2.0 * (10.0 / TWO_PI_) * dec2 * mult / (double)M_;
    }
    __syncthreads();

    const int d = blockIdx.x * 256 + threadIdx.x;
    if (d > 1024) return;

    double acc = 0.0;
    if (jc == 0) {   // j = 0 term, added once
        double mult0;
        if (c == 0) {
            double s = 5.0 * (double)s0[0];
            mult0 = -(double)a0[0] * 4.0 * PI_ / (s * s);
        } else {
            double s = 5.0 * (double)s1[0];
            mult0 = (double)a1[0] * 4.0 * PI_ / ((s * s) * (s * s));
        }
        acc = (10.0 / TWO_PI_) * (PI_ / TAU_) * mult0 / (double)M_;
    }

    int r = (int)(((long long)jlo * (long long)d) % M_);
    #pragma unroll 4
    for (int jj = 0; jj < 1024 / H_JSPLIT; ++jj) {
        acc += coeff[jj] * costab[r];
        r += d; if (r >= M_) r -= M_;
    }
    atomicAdd(&hhalf[c * 1025 + d], acc);
}

// ---------------------------------------------------------------------------
// conv[b][c][m] += sum over this block's mp-chunk of gsum[b][mp]*h_c[(m-mp) mod M]
// BOTH channels per block: one scalar gs load feeds two independent FMA
// chains (8 accumulators total).  h windows staged to LDS (mirror+mod folded
// at staging -> wrap-free inner loop).  mp split CV_SPLIT ways; f64 atomicAdd
// into pre-zeroed conv.
// ---------------------------------------------------------------------------
__global__ void conv_kernel(const double* __restrict__ gsum, const double* __restrict__ hhalf,
                            double* __restrict__ conv) {
    __shared__ double hwin0[512];
    __shared__ double hwin1[512];
    const int mt = blockIdx.x;          // m-tile, 0..8
    const int s  = blockIdx.y;          // mp-chunk, 0..CV_SPLIT-1
    const int b  = blockIdx.z;
    const int m0  = mt * 256;
    const int p0  = (s * M_) / CV_SPLIT;
    const int p1  = ((s + 1) * M_) / CV_SPLIT;
    const int len = p1 - p0;            // 256 or 257
    const int base = m0 - (p0 + len - 1) + M_;   // >= 1
    const int win  = 255 + len;                  // <= 512
    for (int i = threadIdx.x; i < win; i += 256) {
        int idx = base + i;
        while (idx >= M_) idx -= M_;
        int d = (idx > 1024) ? (M_ - idx) : idx;   // h even: h[d] = hhalf[min(d,M-d)]
        hwin0[i] = hhalf[d];
        hwin1[i] = hhalf[1025 + d];
    }
    __syncthreads();
    const int m = m0 + threadIdx.x;
    if (m >= M_) return;
    const double* gs = gsum + (size_t)b * M_ + p0;   // wave-uniform index -> s_load
    const int i0 = threadIdx.x + len - 1;
    double a00 = 0.0, a01 = 0.0, a02 = 0.0, a03 = 0.0;
    double a10 = 0.0, a11 = 0.0, a12 = 0.0, a13 = 0.0;
    int mp = 0;
    #pragma unroll 2
    for (; mp + 3 < len; mp += 4) {
        double g0 = gs[mp+0], g1 = gs[mp+1], g2 = gs[mp+2], g3 = gs[mp+3];
        const double* h0 = hwin0 + (i0 - mp);
        const double* h1 = hwin1 + (i0 - mp);
        a00 += g0 * h0[0];  a10 += g0 * h1[0];
        a01 += g1 * h0[-1]; a11 += g1 * h1[-1];
        a02 += g2 * h0[-2]; a12 += g2 * h1[-2];
        a03 += g3 * h0[-3]; a13 += g3 * h1[-3];
    }
    for (; mp < len; ++mp) {
        double g = gs[mp];
        a00 += g * hwin0[i0 - mp];
        a10 += g * hwin1[i0 - mp];
    }
    double* cv = conv + (size_t)b * 2 * M_ + m;
    atomicAdd(cv,      (a00 + a01) + (a02 + a03));
    atomicAdd(cv + M_, (a10 + a11) + (a12 + a13));
}

// ---------------------------------------------------------------------------
// fmm[b][n][c] = (1/M) sum_m g[b,n,m] * conv[b][c][m]
// FMM_LPP lanes per point; contiguous 128B window reads; shfl-xor reduce.
// ---------------------------------------------------------------------------
__global__ void fmm_kernel(const float* __restrict__ x, const double* __restrict__ conv,
                           float* __restrict__ out) {
    const int gid = blockIdx.x * 256 + threadIdx.x;
    const int pt  = gid / FMM_LPP;     // point id = b*N + n
    const int sub = gid % FMM_LPP;
    const int b   = pt >> 10;          // / N_
    const double du      = TWO_PI_ / (double)M_;
    const double inv4tau = 1.0 / (4.0 * TAU_);
    const double u = (double)x[pt] * (TWO_PI_ / 10.0);
    int mc = (int)(u / du + 0.5);
    int lo = mc - 34; if (lo < 0) lo = 0;
    int hi = mc + 34; if (hi > M_ - 1) hi = M_ - 1;
    const double* c0 = conv + (size_t)(b * 2) * M_;
    const double* c1 = c0 + M_;
    double a0 = 0.0, a1 = 0.0;
    for (int m = lo + sub; m <= hi; m += FMM_LPP) {
        double d = u - du * (double)m;
        double g = (double)__expf(-(float)(d * d * inv4tau));
        a0 += g * c0[m];
        a1 += g * c1[m];
    }
    a0 += __shfl_xor(a0, 1); a1 += __shfl_xor(a1, 1);
    a0 += __shfl_xor(a0, 2); a1 += __shfl_xor(a1, 2);
    a0 += __shfl_xor(a0, 4); a1 += __shfl_xor(a1, 4);
    a0 += __shfl_xor(a0, 8); a1 += __shfl_xor(a1, 8);
    if (sub == 0) {
        out[pt * 2 + 0] = (float)(a0 / (double)M_);
        out[pt * 2 + 1] = (float)(a1 / (double)M_);
    }
}

// ---------------------------------------------------------------------------
extern "C" void kernel_launch(void* const* d_in, const int* in_sizes, int n_in,
                              void* d_out, int out_size, void* d_ws, size_t ws_size,
                              hipStream_t stream) {
    (void)in_sizes; (void)n_in; (void)out_size; (void)ws_size;
    const float* x  = (const float*)d_in[0];
    const float* s0 = (const float*)d_in[1];
    const float* a0 = (const float*)d_in[2];
    const float* s1 = (const float*)d_in[3];
    const float* a1 = (const float*)d_in[4];
    float* out = (float*)d_out;

    // Workspace layout (f64, contiguous): [gsum B*M | hhalf 2*1025 | conv B*2*M]
    double* gsum  = (double*)d_ws;             // 32784
    double* hhalf = gsum + B_ * M_;            // 2050
    double* conv  = hhalf + 2 * 1025;          // 65568

    // Zero all atomic-accumulated regions in one shot (~803 KB)
    hipMemsetAsync(d_ws, 0, (size_t)(B_ * M_ + 2 * 1025 + B_ * 2 * M_) * sizeof(double), stream);

    hipLaunchKernelGGL(gsum_kernel, dim3(9, B_, GS_SPLIT), dim3(256), 0, stream, x, gsum);
    hipLaunchKernelGGL(h_kernel, dim3(5, H_JSPLIT, 2), dim3(256), 0, stream,
                       s0, a0, s1, a1, hhalf);
    hipLaunchKernelGGL(conv_kernel, dim3(9, CV_SPLIT, B_), dim3(256), 0, stream,
                       gsum, hhalf, conv);
    hipLaunchKernelGGL(fmm_kernel, dim3(B_ * N_ * FMM_LPP / 256), dim3(256), 0, stream,
                       x, conv, out);
}

// Round 5
// 97.924 us; speedup vs baseline: 5.0263x; 1.2023x over previous
//
#include <hip/hip_runtime.h>
#include <math.h>

#define M_   2049
#define B_   16
#define N_   1024
#define TAU_ 2.821e-5
#define PI_  3.14159265358979323846
#define TWO_PI_ 6.283185307179586476925286766559

#define GS_CH    8      // point-chunks per batch in the scatter spread
#define H_JSPLIT 16     // j-split for h part (chunks of 64 over j=1..1024)
#define CV_SPLIT 8      // mp-split for conv_kernel
#define FMM_LPP  16     // lanes per point in fmm_kernel

// ---------------------------------------------------------------------------
// Fused kernel 1:
//  blocks [0, GS_CH*B_):      gsum scatter — each point adds its 68-bin
//    Gaussian window into LDS bins (ds_add_f64), then one drain pass of
//    global f64 atomics.  30x less arithmetic than the m-gather (only ~3%
//    of (m,n) pairs are inside the +-33-bin support where t<88).
//  blocks [GS_CH*B_, +160):   h kernel — hhalf[c][d] = (1/M)(W0 +
//    2 sum_j Wj cos(2pi j d/M)) via mirrored LDS cos table + exact
//    incremental (j*d) mod M; j-split, atomicAdd into pre-zeroed hhalf.
// ---------------------------------------------------------------------------
__global__ void spread_h_kernel(const float* __restrict__ x,
                                const float* __restrict__ s0, const float* __restrict__ a0,
                                const float* __restrict__ s1, const float* __restrict__ a1,
                                double* __restrict__ gsum, double* __restrict__ hhalf) {
    __shared__ double smem[M_ + 64];
    const int bx = blockIdx.x;

    if (bx < GS_CH * B_) {
        // ---- gsum scatter part ----
        const int b  = bx / GS_CH;
        const int ch = bx % GS_CH;
        for (int i = threadIdx.x; i < M_; i += 256) smem[i] = 0.0;
        __syncthreads();
        const int pl  = threadIdx.x >> 1;          // local point 0..127
        const int sub = threadIdx.x & 1;           // half-window 0/1
        const double du      = TWO_PI_ / (double)M_;
        const double inv4tau = 1.0 / (4.0 * TAU_);
        const double u = (double)x[b * N_ + ch * (N_ / GS_CH) + pl] * (TWO_PI_ / 10.0);
        const int mc = (int)(u / du + 0.5);
        const int start = mc - 33 + sub * 34;      // covers mc-33 .. mc+34
        for (int i = 0; i < 34; ++i) {
            int m = start + i;
            if (m >= 0 && m < M_) {
                double d = u - du * (double)m;
                double t = d * d * inv4tau;
                if (t < 88.0) atomicAdd(&smem[m], (double)__expf(-(float)t));
            }
        }
        __syncthreads();
        for (int i = threadIdx.x; i < M_; i += 256) {
            double v = smem[i];
            if (v != 0.0) atomicAdd(&gsum[b * M_ + i], v);
        }
    } else {
        // ---- h part ----
        const int t  = bx - GS_CH * B_;
        const int dt = t % 5;                      // d-tile 0..4
        const int jc = (t / 5) % H_JSPLIT;         // j-chunk
        const int c  = t / (5 * H_JSPLIT);         // channel
        double* costab = smem;                     // 2049
        double* coeff  = smem + M_;                // 64
        const int jlo = 1 + jc * (1024 / H_JSPLIT);
        const double ang0 = TWO_PI_ / (double)M_;

        // mirrored cos table: cos(2pi (M-i)/M) = cos(2pi i/M)
        for (int i = threadIdx.x; i <= 1024; i += 256) {
            double v = cos(ang0 * (double)i);
            costab[i] = v;
            if (i > 0) costab[M_ - i] = v;
        }
        if (threadIdx.x < 1024 / H_JSPLIT) {
            int j = jlo + threadIdx.x;
            double k2   = (double)j * (double)j;
            double dec2 = (PI_ / TAU_) * exp(2.0 * TAU_ * k2);   // deconv^2
            double mult;
            if (c == 0) {
                double s = 5.0 * (double)s0[0];
                mult = -(double)a0[0] * 4.0 * PI_ / (k2 + s * s);
            } else {
                double s = 5.0 * (double)s1[0];
                double den = k2 + s * s;
                mult = (double)a1[0] * 4.0 * PI_ / (den * den);
            }
            coeff[threadIdx.x] = 2.0 * (10.0 / TWO_PI_) * dec2 * mult / (double)M_;
        }
        __syncthreads();

        const int d = dt * 256 + threadIdx.x;
        if (d > 1024) return;

        double acc = 0.0;
        if (jc == 0) {   // j = 0 term, added once
            double mult0;
            if (c == 0) {
                double s = 5.0 * (double)s0[0];
                mult0 = -(double)a0[0] * 4.0 * PI_ / (s * s);
            } else {
                double s = 5.0 * (double)s1[0];
                mult0 = (double)a1[0] * 4.0 * PI_ / ((s * s) * (s * s));
            }
            acc = (10.0 / TWO_PI_) * (PI_ / TAU_) * mult0 / (double)M_;
        }
        int r = (int)(((long long)jlo * (long long)d) % M_);
        #pragma unroll 4
        for (int jj = 0; jj < 1024 / H_JSPLIT; ++jj) {
            acc += coeff[jj] * costab[r];
            r += d; if (r >= M_) r -= M_;
        }
        atomicAdd(&hhalf[c * 1025 + d], acc);
    }
}

// ---------------------------------------------------------------------------
// conv[b][c][m] += sum over this block's mp-chunk of gsum[b][mp]*h_c[(m-mp) mod M]
// Both channels per block (one scalar gs load feeds two chains); h windows in
// LDS, wrap folded at staging; unroll-8 with 8 f64 accumulator chains
// (dep distance ~32 cyc covers f64-FMA + LDS latency at 4.5 waves/SIMD).
// ---------------------------------------------------------------------------
__global__ void conv_kernel(const double* __restrict__ gsum, const double* __restrict__ hhalf,
                            double* __restrict__ conv) {
    __shared__ double hwin0[512];
    __shared__ double hwin1[512];
    const int mt = blockIdx.x;          // m-tile, 0..8
    const int s  = blockIdx.y;          // mp-chunk, 0..CV_SPLIT-1
    const int b  = blockIdx.z;
    const int m0  = mt * 256;
    const int p0  = (s * M_) / CV_SPLIT;
    const int p1  = ((s + 1) * M_) / CV_SPLIT;
    const int len = p1 - p0;            // 256 or 257
    const int base = m0 - (p0 + len - 1) + M_;   // >= 1
    const int win  = 255 + len;                  // <= 512
    for (int i = threadIdx.x; i < win; i += 256) {
        int idx = base + i;
        while (idx >= M_) idx -= M_;
        int d = (idx > 1024) ? (M_ - idx) : idx;   // h even: h[d] = hhalf[min(d,M-d)]
        hwin0[i] = hhalf[d];
        hwin1[i] = hhalf[1025 + d];
    }
    __syncthreads();
    const int m = m0 + threadIdx.x;
    if (m >= M_) return;
    const double* gs = gsum + (size_t)b * M_ + p0;   // wave-uniform -> scalar loads
    const int i0 = threadIdx.x + len - 1;
    double a00 = 0.0, a01 = 0.0, a02 = 0.0, a03 = 0.0;
    double a10 = 0.0, a11 = 0.0, a12 = 0.0, a13 = 0.0;
    int mp = 0;
    for (; mp + 7 < len; mp += 8) {
        double g0 = gs[mp+0], g1 = gs[mp+1], g2 = gs[mp+2], g3 = gs[mp+3];
        double g4 = gs[mp+4], g5 = gs[mp+5], g6 = gs[mp+6], g7 = gs[mp+7];
        const double* h0 = hwin0 + (i0 - mp - 7);   // ascending 8-double span
        const double* h1 = hwin1 + (i0 - mp - 7);
        a00 += g0 * h0[7];  a10 += g0 * h1[7];
        a01 += g1 * h0[6];  a11 += g1 * h1[6];
        a02 += g2 * h0[5];  a12 += g2 * h1[5];
        a03 += g3 * h0[4];  a13 += g3 * h1[4];
        a00 += g4 * h0[3];  a10 += g4 * h1[3];
        a01 += g5 * h0[2];  a11 += g5 * h1[2];
        a02 += g6 * h0[1];  a12 += g6 * h1[1];
        a03 += g7 * h0[0];  a13 += g7 * h1[0];
    }
    for (; mp < len; ++mp) {
        double g = gs[mp];
        a00 += g * hwin0[i0 - mp];
        a10 += g * hwin1[i0 - mp];
    }
    double* cv = conv + (size_t)b * 2 * M_ + m;
    atomicAdd(cv,      (a00 + a01) + (a02 + a03));
    atomicAdd(cv + M_, (a10 + a11) + (a12 + a13));
}

// ---------------------------------------------------------------------------
// fmm[b][n][c] = (1/M) sum_m g[b,n,m] * conv[b][c][m]
// FMM_LPP lanes per point; contiguous 128B window reads; shfl-xor reduce.
// ---------------------------------------------------------------------------
__global__ void fmm_kernel(const float* __restrict__ x, const double* __restrict__ conv,
                           float* __restrict__ out) {
    const int gid = blockIdx.x * 256 + threadIdx.x;
    const int pt  = gid / FMM_LPP;     // point id = b*N + n
    const int sub = gid % FMM_LPP;
    const int b   = pt >> 10;          // / N_
    const double du      = TWO_PI_ / (double)M_;
    const double inv4tau = 1.0 / (4.0 * TAU_);
    const double u = (double)x[pt] * (TWO_PI_ / 10.0);
    int mc = (int)(u / du + 0.5);
    int lo = mc - 34; if (lo < 0) lo = 0;
    int hi = mc + 34; if (hi > M_ - 1) hi = M_ - 1;
    const double* c0 = conv + (size_t)(b * 2) * M_;
    const double* c1 = c0 + M_;
    double a0 = 0.0, a1 = 0.0;
    for (int m = lo + sub; m <= hi; m += FMM_LPP) {
        double d = u - du * (double)m;
        double g = (double)__expf(-(float)(d * d * inv4tau));
        a0 += g * c0[m];
        a1 += g * c1[m];
    }
    a0 += __shfl_xor(a0, 1); a1 += __shfl_xor(a1, 1);
    a0 += __shfl_xor(a0, 2); a1 += __shfl_xor(a1, 2);
    a0 += __shfl_xor(a0, 4); a1 += __shfl_xor(a1, 4);
    a0 += __shfl_xor(a0, 8); a1 += __shfl_xor(a1, 8);
    if (sub == 0) {
        out[pt * 2 + 0] = (float)(a0 / (double)M_);
        out[pt * 2 + 1] = (float)(a1 / (double)M_);
    }
}

// ---------------------------------------------------------------------------
extern "C" void kernel_launch(void* const* d_in, const int* in_sizes, int n_in,
                              void* d_out, int out_size, void* d_ws, size_t ws_size,
                              hipStream_t stream) {
    (void)in_sizes; (void)n_in; (void)out_size; (void)ws_size;
    const float* x  = (const float*)d_in[0];
    const float* s0 = (const float*)d_in[1];
    const float* a0 = (const float*)d_in[2];
    const float* s1 = (const float*)d_in[3];
    const float* a1 = (const float*)d_in[4];
    float* out = (float*)d_out;

    // Workspace layout (f64, contiguous): [gsum B*M | hhalf 2*1025 | conv B*2*M]
    double* gsum  = (double*)d_ws;             // 32784
    double* hhalf = gsum + B_ * M_;            // 2050
    double* conv  = hhalf + 2 * 1025;          // 65568

    // Zero all atomic-accumulated regions in one shot (~803 KB)
    hipMemsetAsync(d_ws, 0, (size_t)(B_ * M_ + 2 * 1025 + B_ * 2 * M_) * sizeof(double), stream);

    hipLaunchKernelGGL(spread_h_kernel, dim3(GS_CH * B_ + 5 * H_JSPLIT * 2), dim3(256), 0,
                       stream, x, s0, a0, s1, a1, gsum, hhalf);
    hipLaunchKernelGGL(conv_kernel, dim3(9, CV_SPLIT, B_), dim3(256), 0, stream,
                       gsum, hhalf, conv);
    hipLaunchKernelGGL(fmm_kernel, dim3(B_ * N_ * FMM_LPP / 256), dim3(256), 0, stream,
                       x, conv, out);
}